// Round 18
// baseline (19999.435 us; speedup 1.0000x reference)
//
#include <hip/hip_runtime.h>
#include <hip/hip_cooperative_groups.h>
#include <math.h>
#include <stdint.h>

// ReLSTM_18940805775611 — B=512, T=128, H=512, 2-layer LSTM, 128 TF + 127 AR.
// fp32 in / fp32 out. R17 (bf16 MFMA, 513 dispatches): 6.06 ms, absmax 1.22e-4.
// R18: persistent cooperative kernel — the whole 255-step recurrence in ONE
// launch, cg::grid.sync() between layer phases (511 syncs replace ~513
// serialized ~4-6us dispatch overheads). Same MFMA tiling as R17 (16x16x32
// bf16, fp32 acc; block = 64 batch x 16 j x 4 gates; verified C/D map ->
// lane-local LSTM epilogue). XCD locality: m0 = (blk&7)*64 pins each XCD to a
// fixed batch slice (h/c traffic XCD-local; c1/c2 block-private).
// Reference quirk kept: y0 from CELL state c2.

namespace cg = cooperative_groups;

namespace {
constexpr int NH  = 512;    // hidden
constexpr int NT  = 128;    // seq len
constexpr int NB  = 512;    // batch
constexpr int KC  = 64;     // k-chunk
constexpr int LDK = KC + 8; // LDS row stride (bf16 elems)
}

typedef __attribute__((ext_vector_type(8))) short bf16x8;
typedef __attribute__((ext_vector_type(4))) float f32x4;

// Present in case the harness resolves this symbol.
__global__ void ReLSTM_18940805775611_kernel() {}

__device__ __forceinline__ unsigned short lstm8_f2b(float f) {
    union { float f; uint32_t i; } v; v.f = f;
    const uint32_t r = v.i + 0x7FFFu + ((v.i >> 16) & 1u);   // RNE
    return (unsigned short)(r >> 16);
}
__device__ __forceinline__ float lstm8_sig(float x) {
    return 1.0f / (1.0f + expf(-x));
}

// ---- sentinel 2.0625f: truncation diagnostic ----
__global__ void lstm8_mark(float* out) {
    const int i = blockIdx.x * blockDim.x + threadIdx.x;
    if (i < NB * NT) out[i] = 2.0625f;
}

// ---- one-time prep: weights fp32->bf16 (RNE), summed biases, zero states,
// ybuf := b_lin ----
__global__ void lstm8_prep(
    const float* whh0, const float* wih1, const float* whh1,
    const float* bih0, const float* bhh0, const float* bih1, const float* bhh1,
    const float* blin,
    unsigned short* wb0, unsigned short* wb1i, unsigned short* wb1h,
    float* bsum0, float* bsum1,
    unsigned short* hz, float* cz, float* ybuf)
{
    const size_t stride = (size_t)gridDim.x * blockDim.x;
    const size_t i0 = (size_t)blockIdx.x * blockDim.x + threadIdx.x;
    const size_t NW = (size_t)4 * NH * NH;
    for (size_t i = i0; i < NW; i += stride) {
        wb0 [i] = lstm8_f2b(whh0[i]);
        wb1i[i] = lstm8_f2b(wih1[i]);
        wb1h[i] = lstm8_f2b(whh1[i]);
    }
    for (size_t i = i0; i < (size_t)4 * NH; i += stride) {
        bsum0[i] = bih0[i] + bhh0[i];
        bsum1[i] = bih1[i] + bhh1[i];
    }
    for (size_t i = i0; i < (size_t)4 * NB * NH; i += stride) hz[i] = 0;
    for (size_t i = i0; i < (size_t)2 * NB * NH; i += stride) cz[i] = 0.0f;
    const float bl = blin[0];
    for (size_t i = i0; i < (size_t)NB * NT; i += stride) ybuf[i] = bl;
}

// ---- layer-0 cell body: gates = x*w_ih0 + hPrev @ w_hh0^T + bsum0 ----
__device__ __forceinline__ void lstm8_cell0(
    const unsigned short* __restrict__ hprev, unsigned short* __restrict__ hnext,
    float* __restrict__ c1, const unsigned short* __restrict__ wb0,
    const float* xv,
    float b0i, float b0f, float b0g, float b0o,
    float wxi, float wxf, float wxg, float wxo,
    int m0, int j0, int tid,
    unsigned short (*Ash)[LDK], unsigned short (*Bsh)[LDK])
{
    const int lane = tid & 63;
    const int wv = tid >> 6, quad = lane >> 4, ln15 = lane & 15;
    const int ldr = tid >> 3, seg = tid & 7;
    const int jv = j0 + ln15;
    f32x4 a0 = {0.f, 0.f, 0.f, 0.f};
    f32x4 a1 = a0, a2 = a0, a3 = a0;
    for (int kc = 0; kc < NH; kc += KC) {
        *(uint4*)&Ash[ldr][seg * 8] =
            *(const uint4*)(hprev + (size_t)(m0 + ldr) * NH + kc + seg * 8);
        *(uint4*)&Ash[ldr + 32][seg * 8] =
            *(const uint4*)(hprev + (size_t)(m0 + ldr + 32) * NH + kc + seg * 8);
        const size_t g0 = (size_t)((ldr >> 4) * NH + j0 + (ldr & 15)) * NH;
        const size_t g1 = (size_t)(((ldr + 32) >> 4) * NH + j0 + ((ldr + 32) & 15)) * NH;
        *(uint4*)&Bsh[ldr][seg * 8] = *(const uint4*)(wb0 + g0 + kc + seg * 8);
        *(uint4*)&Bsh[ldr + 32][seg * 8] = *(const uint4*)(wb0 + g1 + kc + seg * 8);
        __syncthreads();
        #pragma unroll
        for (int ks = 0; ks < KC; ks += 32) {
            const bf16x8 af = *(const bf16x8*)&Ash[wv * 16 + ln15][ks + quad * 8];
            const bf16x8 bb0 = *(const bf16x8*)&Bsh[ln15][ks + quad * 8];
            const bf16x8 bb1 = *(const bf16x8*)&Bsh[16 + ln15][ks + quad * 8];
            const bf16x8 bb2 = *(const bf16x8*)&Bsh[32 + ln15][ks + quad * 8];
            const bf16x8 bb3 = *(const bf16x8*)&Bsh[48 + ln15][ks + quad * 8];
            a0 = __builtin_amdgcn_mfma_f32_16x16x32_bf16(af, bb0, a0, 0, 0, 0);
            a1 = __builtin_amdgcn_mfma_f32_16x16x32_bf16(af, bb1, a1, 0, 0, 0);
            a2 = __builtin_amdgcn_mfma_f32_16x16x32_bf16(af, bb2, a2, 0, 0, 0);
            a3 = __builtin_amdgcn_mfma_f32_16x16x32_bf16(af, bb3, a3, 0, 0, 0);
        }
        __syncthreads();
    }
    #pragma unroll
    for (int r = 0; r < 4; ++r) {
        const int m = m0 + wv * 16 + quad * 4 + r;
        const float gi = a0[r] + fmaf(xv[r], wxi, b0i);
        const float gf = a1[r] + fmaf(xv[r], wxf, b0f);
        const float gg = a2[r] + fmaf(xv[r], wxg, b0g);
        const float go = a3[r] + fmaf(xv[r], wxo, b0o);
        float cv = c1[(size_t)m * NH + jv];
        cv = lstm8_sig(gf) * cv + lstm8_sig(gi) * tanhf(gg);
        c1[(size_t)m * NH + jv] = cv;
        hnext[(size_t)m * NH + jv] = lstm8_f2b(lstm8_sig(go) * tanhf(cv));
    }
}

// ---- layer-1 cell body: gates = h1 @ w_ih1^T + h2 @ w_hh1^T + bsum1 ----
__device__ __forceinline__ void lstm8_cell1(
    const unsigned short* __restrict__ h1cur, const unsigned short* __restrict__ h2prev,
    unsigned short* __restrict__ h2next, float* __restrict__ c2,
    const unsigned short* __restrict__ wb1i, const unsigned short* __restrict__ wb1h,
    float b1i, float b1f, float b1g, float b1o, float wl,
    float* __restrict__ ybuf, int ycol,
    int m0, int j0, int tid,
    unsigned short (*Ash)[LDK], unsigned short (*Bsh)[LDK], float (*redsh)[17])
{
    const int lane = tid & 63;
    const int wv = tid >> 6, quad = lane >> 4, ln15 = lane & 15;
    const int ldr = tid >> 3, seg = tid & 7;
    const int jv = j0 + ln15;
    f32x4 a0 = {0.f, 0.f, 0.f, 0.f};
    f32x4 a1 = a0, a2 = a0, a3 = a0;
    #pragma unroll 1
    for (int ph = 0; ph < 2; ++ph) {
        const unsigned short* ap = ph ? h2prev : h1cur;
        const unsigned short* bp = ph ? wb1h : wb1i;
        for (int kc = 0; kc < NH; kc += KC) {
            *(uint4*)&Ash[ldr][seg * 8] =
                *(const uint4*)(ap + (size_t)(m0 + ldr) * NH + kc + seg * 8);
            *(uint4*)&Ash[ldr + 32][seg * 8] =
                *(const uint4*)(ap + (size_t)(m0 + ldr + 32) * NH + kc + seg * 8);
            const size_t g0 = (size_t)((ldr >> 4) * NH + j0 + (ldr & 15)) * NH;
            const size_t g1 = (size_t)(((ldr + 32) >> 4) * NH + j0 + ((ldr + 32) & 15)) * NH;
            *(uint4*)&Bsh[ldr][seg * 8] = *(const uint4*)(bp + g0 + kc + seg * 8);
            *(uint4*)&Bsh[ldr + 32][seg * 8] = *(const uint4*)(bp + g1 + kc + seg * 8);
            __syncthreads();
            #pragma unroll
            for (int ks = 0; ks < KC; ks += 32) {
                const bf16x8 af = *(const bf16x8*)&Ash[wv * 16 + ln15][ks + quad * 8];
                const bf16x8 bb0 = *(const bf16x8*)&Bsh[ln15][ks + quad * 8];
                const bf16x8 bb1 = *(const bf16x8*)&Bsh[16 + ln15][ks + quad * 8];
                const bf16x8 bb2 = *(const bf16x8*)&Bsh[32 + ln15][ks + quad * 8];
                const bf16x8 bb3 = *(const bf16x8*)&Bsh[48 + ln15][ks + quad * 8];
                a0 = __builtin_amdgcn_mfma_f32_16x16x32_bf16(af, bb0, a0, 0, 0, 0);
                a1 = __builtin_amdgcn_mfma_f32_16x16x32_bf16(af, bb1, a1, 0, 0, 0);
                a2 = __builtin_amdgcn_mfma_f32_16x16x32_bf16(af, bb2, a2, 0, 0, 0);
                a3 = __builtin_amdgcn_mfma_f32_16x16x32_bf16(af, bb3, a3, 0, 0, 0);
            }
            __syncthreads();
        }
    }
    float hv[4];
    #pragma unroll
    for (int r = 0; r < 4; ++r) {
        const int m = m0 + wv * 16 + quad * 4 + r;
        const float gi = a0[r] + b1i;
        const float gf = a1[r] + b1f;
        const float gg = a2[r] + b1g;
        const float go = a3[r] + b1o;
        float cv = c2[(size_t)m * NH + jv];
        cv = lstm8_sig(gf) * cv + lstm8_sig(gi) * tanhf(gg);
        c2[(size_t)m * NH + jv] = cv;
        hv[r] = lstm8_sig(go) * tanhf(cv);
        h2next[(size_t)m * NH + jv] = lstm8_f2b(hv[r]);
    }
    if (ycol >= 0) {
        #pragma unroll
        for (int r = 0; r < 4; ++r)
            redsh[wv * 16 + quad * 4 + r][ln15] = hv[r] * wl;
        __syncthreads();
        if (tid < 64) {
            float s = 0.0f;
            #pragma unroll
            for (int j = 0; j < 16; ++j) s += redsh[tid][j];
            atomicAdd(&ybuf[(size_t)(m0 + tid) * NT + ycol], s);
        }
        __syncthreads();
    }
}

// ---- persistent kernel: entire 255-step recurrence, cooperative launch ----
__global__ __launch_bounds__(256) void lstm8_persist(
    const float* xin, float* ybuf, float* outf,
    unsigned short* h1a, unsigned short* h1b,
    unsigned short* h2a, unsigned short* h2b,
    float* c1, float* c2,
    const unsigned short* wb0, const unsigned short* wb1i, const unsigned short* wb1h,
    const float* bsum0, const float* bsum1,
    const float* wih0f, const float* wlinf, const float* blin)
{
    __shared__ unsigned short Ash[64][LDK];
    __shared__ unsigned short Bsh[64][LDK];
    __shared__ float redsh[64][17];
    cg::grid_group grid = cg::this_grid();

    const int blk = blockIdx.x;
    const int m0 = (blk & 7) * 64;     // XCD-aligned batch slice
    const int j0 = (blk >> 3) * 16;
    const int tid = threadIdx.x;
    const int lane = tid & 63;
    const int wv = tid >> 6, quad = lane >> 4, ln15 = lane & 15;
    const int jv = j0 + ln15;
    const int mbase = m0 + wv * 16 + quad * 4;

    const float b0i = bsum0[jv],          b0f = bsum0[NH + jv];
    const float b0g = bsum0[2 * NH + jv], b0o = bsum0[3 * NH + jv];
    const float wxi = wih0f[jv],          wxf = wih0f[NH + jv];
    const float wxg = wih0f[2 * NH + jv], wxo = wih0f[3 * NH + jv];
    const float b1i = bsum1[jv],          b1f = bsum1[NH + jv];
    const float b1g = bsum1[2 * NH + jv], b1o = bsum1[3 * NH + jv];
    const float wl  = wlinf[jv];

    unsigned short* h1p[2] = { h1a, h1b };
    unsigned short* h2p[2] = { h2a, h2b };
    int p = 0;

    // ---- Phase 1: teacher-forced over x[:, t] ----
    for (int t = 0; t < NT; ++t) {
        float xv[4];
        #pragma unroll
        for (int r = 0; r < 4; ++r)
            xv[r] = xin[(size_t)(mbase + r) * NT + t];
        lstm8_cell0(h1p[p], h1p[p ^ 1], c1, wb0, xv,
                    b0i, b0f, b0g, b0o, wxi, wxf, wxg, wxo,
                    m0, j0, tid, Ash, Bsh);
        grid.sync();
        lstm8_cell1(h1p[p ^ 1], h2p[p], h2p[p ^ 1], c2, wb1i, wb1h,
                    b1i, b1f, b1g, b1o, wl, ybuf, -1,
                    m0, j0, tid, Ash, Bsh, redsh);
        grid.sync();
        p ^= 1;
    }

    // ---- y0 head (reference quirk): y[:,0] = b_lin + c2 @ w_lin (CELL!) ----
    {
        float* rf = &redsh[0][0];
        const float bl = blin[0];
        #pragma unroll 1
        for (int rr = 0; rr < 2; ++rr) {
            const int b = blk * 2 + rr;
            rf[tid] = c2[(size_t)b * NH + tid]       * wlinf[tid]
                    + c2[(size_t)b * NH + tid + 256] * wlinf[tid + 256];
            __syncthreads();
            for (int off = 128; off > 0; off >>= 1) {
                if (tid < off) rf[tid] += rf[tid + off];
                __syncthreads();
            }
            if (tid == 0) ybuf[(size_t)b * NT] = bl + rf[0];
            __syncthreads();
        }
    }
    grid.sync();

    // ---- Phase 2: autoregressive; input = y[:, k-1]; head -> y[:, k] ----
    for (int k = 1; k < NT; ++k) {
        float xv[4];
        #pragma unroll
        for (int r = 0; r < 4; ++r)
            xv[r] = ybuf[(size_t)(mbase + r) * NT + (k - 1)];
        lstm8_cell0(h1p[p], h1p[p ^ 1], c1, wb0, xv,
                    b0i, b0f, b0g, b0o, wxi, wxf, wxg, wxo,
                    m0, j0, tid, Ash, Bsh);
        grid.sync();
        lstm8_cell1(h1p[p ^ 1], h2p[p], h2p[p ^ 1], c2, wb1i, wb1h,
                    b1i, b1f, b1g, b1o, wl, ybuf, k,
                    m0, j0, tid, Ash, Bsh, redsh);
        grid.sync();
        p ^= 1;
    }

    // ---- emit all predictions to d_out as fp32 ----
    for (int i = blk * 256 + tid; i < NB * NT; i += 256 * 256)
        outf[i] = ybuf[i];
}

extern "C" void kernel_launch(void* const* d_in, const int* in_sizes, int n_in,
                              void* d_out, int out_size, void* d_ws, size_t ws_size,
                              hipStream_t stream)
{
    int base = 3;
    if (!(n_in > 3 && in_sizes[3] == 4 * NH)) {
        for (int i = 1; i + 9 < n_in; ++i)
            if (in_sizes[i] == 4 * NH) { base = i; break; }
    }
    const float* xin  = (const float*)d_in[0];
    const float* wih0 = (const float*)d_in[base + 0];
    const float* whh0 = (const float*)d_in[base + 1];
    const float* bih0 = (const float*)d_in[base + 2];
    const float* bhh0 = (const float*)d_in[base + 3];
    const float* wih1 = (const float*)d_in[base + 4];
    const float* whh1 = (const float*)d_in[base + 5];
    const float* bih1 = (const float*)d_in[base + 6];
    const float* bhh1 = (const float*)d_in[base + 7];
    const float* wlin = (const float*)d_in[base + 8];
    const float* blin = (const float*)d_in[base + 9];
    float* outf = (float*)d_out;

    // ws layout (~10.3 MB): bf16 weights | bf16 h ping-pong | fp32 c, bias, y.
    const size_t NW = (size_t)4 * NH * NH;
    const size_t S  = (size_t)NB * NH;
    unsigned short* wb0  = (unsigned short*)d_ws;
    unsigned short* wb1i = wb0 + NW;
    unsigned short* wb1h = wb1i + NW;
    unsigned short* h1b0 = wb1h + NW;
    unsigned short* h1b1 = h1b0 + S;
    unsigned short* h2b0 = h1b1 + S;
    unsigned short* h2b1 = h2b0 + S;
    float* bsum0 = (float*)(h2b1 + S);
    float* bsum1 = bsum0 + 4 * NH;
    float* c1    = bsum1 + 4 * NH;
    float* c2    = c1 + S;
    float* ybuf  = c2 + S;

    lstm8_mark<<<(NB * NT + 255) / 256, 256, 0, stream>>>(outf);
    lstm8_prep<<<1024, 256, 0, stream>>>(whh0, wih1, whh1, bih0, bhh0, bih1, bhh1,
                                         blin, wb0, wb1i, wb1h, bsum0, bsum1,
                                         h1b0, c1, ybuf);

    void* ka[] = {
        (void*)&xin, (void*)&ybuf, (void*)&outf,
        (void*)&h1b0, (void*)&h1b1, (void*)&h2b0, (void*)&h2b1,
        (void*)&c1, (void*)&c2,
        (void*)&wb0, (void*)&wb1i, (void*)&wb1h,
        (void*)&bsum0, (void*)&bsum1,
        (void*)&wih0, (void*)&wlin, (void*)&blin
    };
    hipLaunchCooperativeKernel((const void*)lstm8_persist,
                               dim3(256), dim3(256), ka, 0, stream);
}

// Round 19
// 5051.834 us; speedup vs baseline: 3.9588x; 3.9588x over previous
//
#include <hip/hip_runtime.h>
#include <math.h>
#include <stdint.h>

// ReLSTM_18940805775611 — B=512, T=128, H=512, 2-layer LSTM, 128 TF + 127 AR.
// fp32 in / fp32 out. History: R17 bf16-MFMA 513-dispatch = 6.06 ms (absmax
// 1.22e-4). R18 persistent+grid.sync = 20 ms REGRESSION — rocprof showed 96%
// idle + 7.8 GB HBM refetch/launch: grid.sync's device fence invalidates the
// non-coherent per-XCD L2s every step, re-streaming weights from HBM. Lesson:
// on MI355X the dispatch boundary IS the cheap grid barrier.
// R19 = R17 skeleton + two fixes:
//  (1) grid flipped to (32 j, 8 m): blk%8 = j-tile%8 -> each XCD only touches
//      ~768KB of weight rows -> weights per-XCD-L2-resident (was: blk%8 = m,
//      every XCD needed all 6MB > 4MB L2 -> L3 thrash).
//  (2) register double-buffer prefetch in the kc loop: next iteration's A/B
//      uint4s load during current MFMA (hides L2/L3 latency with ILP; only
//      4 waves/CU so TLP can't do it).
// Same MFMA tiling (16x16x32 bf16, fp32 acc; 64 batch x 16 j x 4 gates/block;
// verified C/D map -> lane-local LSTM epilogue). y0-from-c2 quirk kept.

namespace {
constexpr int NH  = 512;    // hidden
constexpr int NT  = 128;    // seq len
constexpr int NB  = 512;    // batch
constexpr int KC  = 64;     // k-chunk
constexpr int LDK = KC + 8; // LDS row stride (bf16 elems)
}

typedef __attribute__((ext_vector_type(8))) short bf16x8;
typedef __attribute__((ext_vector_type(4))) float f32x4;

// Present in case the harness resolves this symbol.
__global__ void ReLSTM_18940805775611_kernel() {}

__device__ __forceinline__ unsigned short lstm9_f2b(float f) {
    union { float f; uint32_t i; } v; v.f = f;
    const uint32_t r = v.i + 0x7FFFu + ((v.i >> 16) & 1u);   // RNE
    return (unsigned short)(r >> 16);
}
__device__ __forceinline__ float lstm9_sig(float x) {
    return 1.0f / (1.0f + expf(-x));
}

// ---- sentinel: truncation diagnostic ----
__global__ void lstm9_mark(float* out) {
    const int i = blockIdx.x * blockDim.x + threadIdx.x;
    if (i < NB * NT) out[i] = 2.03125f;
}

// ---- one-time prep: weights fp32->bf16 (RNE), summed biases, zero states,
// ybuf := b_lin ----
__global__ void lstm9_prep(
    const float* whh0, const float* wih1, const float* whh1,
    const float* bih0, const float* bhh0, const float* bih1, const float* bhh1,
    const float* blin,
    unsigned short* wb0, unsigned short* wb1i, unsigned short* wb1h,
    float* bsum0, float* bsum1,
    unsigned short* hz, float* cz, float* ybuf)
{
    const size_t stride = (size_t)gridDim.x * blockDim.x;
    const size_t i0 = (size_t)blockIdx.x * blockDim.x + threadIdx.x;
    const size_t NW = (size_t)4 * NH * NH;
    for (size_t i = i0; i < NW; i += stride) {
        wb0 [i] = lstm9_f2b(whh0[i]);
        wb1i[i] = lstm9_f2b(wih1[i]);
        wb1h[i] = lstm9_f2b(whh1[i]);
    }
    for (size_t i = i0; i < (size_t)4 * NH; i += stride) {
        bsum0[i] = bih0[i] + bhh0[i];
        bsum1[i] = bih1[i] + bhh1[i];
    }
    for (size_t i = i0; i < (size_t)4 * NB * NH; i += stride) hz[i] = 0;
    for (size_t i = i0; i < (size_t)2 * NB * NH; i += stride) cz[i] = 0.0f;
    const float bl = blin[0];
    for (size_t i = i0; i < (size_t)NB * NT; i += stride) ybuf[i] = bl;
}

// ---- layer-0 MFMA cell: gates = x*w_ih0 + hPrev @ w_hh0^T + bsum0 ----
// grid (32, 8): x = j/16 (XCD-spread), y = batch/64.
__global__ __launch_bounds__(256) void lstm9_layer0(
    const float* __restrict__ xin, float* __restrict__ ybuf,
    int col, int useY, int pubCol, float* __restrict__ outf,
    const unsigned short* __restrict__ hprev, unsigned short* __restrict__ hnext,
    float* __restrict__ c1,
    const unsigned short* __restrict__ wb0,
    const float* __restrict__ bsum0, const float* __restrict__ wih0f)
{
    __shared__ unsigned short Ash[64][LDK];
    __shared__ unsigned short Bsh[64][LDK];
    const int tid  = threadIdx.x;
    const int lane = tid & 63;
    const int wv   = tid >> 6;
    const int quad = lane >> 4;
    const int ln15 = lane & 15;
    const int j0   = blockIdx.x * 16;
    const int m0   = blockIdx.y * 64;

    if (pubCol >= 0 && blockIdx.x == 0 && blockIdx.y == 0) {
        for (int r = tid; r < NB; r += 256)
            outf[(size_t)r * NT + pubCol] = ybuf[(size_t)r * NT + pubCol];
    }

    float xv[4];
    {
        const int mb = m0 + wv * 16 + quad * 4;
        #pragma unroll
        for (int r = 0; r < 4; ++r)
            xv[r] = useY ? ybuf[(size_t)(mb + r) * NT + col]
                         : xin [(size_t)(mb + r) * NT + col];
    }

    f32x4 a0 = {0.f, 0.f, 0.f, 0.f};
    f32x4 a1 = a0, a2 = a0, a3 = a0;

    const int ldr = tid >> 3;   // 0..31
    const int seg = tid & 7;
    const size_t ga0 = (size_t)(m0 + ldr) * NH + seg * 8;
    const size_t ga1 = (size_t)(m0 + ldr + 32) * NH + seg * 8;
    const size_t gb0 = (size_t)((ldr >> 4) * NH + j0 + (ldr & 15)) * NH + seg * 8;
    const size_t gb1 = (size_t)(((ldr + 32) >> 4) * NH + j0 + ((ldr + 32) & 15)) * NH + seg * 8;

    uint4 ra0 = *(const uint4*)(hprev + ga0);
    uint4 ra1 = *(const uint4*)(hprev + ga1);
    uint4 rb0 = *(const uint4*)(wb0 + gb0);
    uint4 rb1 = *(const uint4*)(wb0 + gb1);

    for (int it = 0; it < NH / KC; ++it) {
        *(uint4*)&Ash[ldr][seg * 8]      = ra0;
        *(uint4*)&Ash[ldr + 32][seg * 8] = ra1;
        *(uint4*)&Bsh[ldr][seg * 8]      = rb0;
        *(uint4*)&Bsh[ldr + 32][seg * 8] = rb1;
        __syncthreads();
        if (it + 1 < NH / KC) {
            const int kc = (it + 1) * KC;
            ra0 = *(const uint4*)(hprev + ga0 + kc);
            ra1 = *(const uint4*)(hprev + ga1 + kc);
            rb0 = *(const uint4*)(wb0 + gb0 + kc);
            rb1 = *(const uint4*)(wb0 + gb1 + kc);
        }
        #pragma unroll
        for (int ks = 0; ks < KC; ks += 32) {
            const bf16x8 af = *(const bf16x8*)&Ash[wv * 16 + ln15][ks + quad * 8];
            const bf16x8 b0 = *(const bf16x8*)&Bsh[ln15][ks + quad * 8];
            const bf16x8 b1 = *(const bf16x8*)&Bsh[16 + ln15][ks + quad * 8];
            const bf16x8 b2 = *(const bf16x8*)&Bsh[32 + ln15][ks + quad * 8];
            const bf16x8 b3 = *(const bf16x8*)&Bsh[48 + ln15][ks + quad * 8];
            a0 = __builtin_amdgcn_mfma_f32_16x16x32_bf16(af, b0, a0, 0, 0, 0);
            a1 = __builtin_amdgcn_mfma_f32_16x16x32_bf16(af, b1, a1, 0, 0, 0);
            a2 = __builtin_amdgcn_mfma_f32_16x16x32_bf16(af, b2, a2, 0, 0, 0);
            a3 = __builtin_amdgcn_mfma_f32_16x16x32_bf16(af, b3, a3, 0, 0, 0);
        }
        __syncthreads();
    }

    const int jv = j0 + ln15;
    const float bi  = bsum0[jv],          bfv = bsum0[NH + jv];
    const float bg  = bsum0[2 * NH + jv], bo  = bsum0[3 * NH + jv];
    const float wxi = wih0f[jv],          wxf = wih0f[NH + jv];
    const float wxg = wih0f[2 * NH + jv], wxo = wih0f[3 * NH + jv];
    #pragma unroll
    for (int r = 0; r < 4; ++r) {
        const int m = m0 + wv * 16 + quad * 4 + r;
        const float gi = a0[r] + fmaf(xv[r], wxi, bi);
        const float gf = a1[r] + fmaf(xv[r], wxf, bfv);
        const float gg = a2[r] + fmaf(xv[r], wxg, bg);
        const float go = a3[r] + fmaf(xv[r], wxo, bo);
        float cv = c1[(size_t)m * NH + jv];
        cv = lstm9_sig(gf) * cv + lstm9_sig(gi) * tanhf(gg);
        c1[(size_t)m * NH + jv] = cv;
        hnext[(size_t)m * NH + jv] = lstm9_f2b(lstm9_sig(go) * tanhf(cv));
    }
}

// ---- layer-1 MFMA cell: gates = h1 @ w_ih1^T + h2 @ w_hh1^T + bsum1 ----
__global__ __launch_bounds__(256) void lstm9_layer1(
    const unsigned short* __restrict__ h1cur, const unsigned short* __restrict__ h2prev,
    unsigned short* __restrict__ h2next, float* __restrict__ c2,
    const unsigned short* __restrict__ wb1i, const unsigned short* __restrict__ wb1h,
    const float* __restrict__ bsum1, const float* __restrict__ wlinf,
    float* __restrict__ ybuf, int ycol)
{
    __shared__ unsigned short Ash[64][LDK];
    __shared__ unsigned short Bsh[64][LDK];
    __shared__ float redsh[64][17];
    const int tid  = threadIdx.x;
    const int lane = tid & 63;
    const int wv   = tid >> 6;
    const int quad = lane >> 4;
    const int ln15 = lane & 15;
    const int j0   = blockIdx.x * 16;
    const int m0   = blockIdx.y * 64;

    f32x4 a0 = {0.f, 0.f, 0.f, 0.f};
    f32x4 a1 = a0, a2 = a0, a3 = a0;

    const int ldr = tid >> 3;
    const int seg = tid & 7;
    const size_t ga0 = (size_t)(m0 + ldr) * NH + seg * 8;
    const size_t ga1 = (size_t)(m0 + ldr + 32) * NH + seg * 8;
    const size_t gb0 = (size_t)((ldr >> 4) * NH + j0 + (ldr & 15)) * NH + seg * 8;
    const size_t gb1 = (size_t)(((ldr + 32) >> 4) * NH + j0 + ((ldr + 32) & 15)) * NH + seg * 8;

    const unsigned short* APs[2] = { h1cur, wb1h ? h2prev : h2prev };
    const unsigned short* BPs[2] = { wb1i, wb1h };
    APs[1] = h2prev;

    uint4 ra0 = *(const uint4*)(h1cur + ga0);
    uint4 ra1 = *(const uint4*)(h1cur + ga1);
    uint4 rb0 = *(const uint4*)(wb1i + gb0);
    uint4 rb1 = *(const uint4*)(wb1i + gb1);

    constexpr int NIT = 2 * (NH / KC);   // 16
    for (int it = 0; it < NIT; ++it) {
        *(uint4*)&Ash[ldr][seg * 8]      = ra0;
        *(uint4*)&Ash[ldr + 32][seg * 8] = ra1;
        *(uint4*)&Bsh[ldr][seg * 8]      = rb0;
        *(uint4*)&Bsh[ldr + 32][seg * 8] = rb1;
        __syncthreads();
        if (it + 1 < NIT) {
            const int ni = it + 1;
            const unsigned short* ap = APs[ni >> 3];
            const unsigned short* bp = BPs[ni >> 3];
            const int kc = (ni & 7) * KC;
            ra0 = *(const uint4*)(ap + ga0 + kc);
            ra1 = *(const uint4*)(ap + ga1 + kc);
            rb0 = *(const uint4*)(bp + gb0 + kc);
            rb1 = *(const uint4*)(bp + gb1 + kc);
        }
        #pragma unroll
        for (int ks = 0; ks < KC; ks += 32) {
            const bf16x8 af = *(const bf16x8*)&Ash[wv * 16 + ln15][ks + quad * 8];
            const bf16x8 b0 = *(const bf16x8*)&Bsh[ln15][ks + quad * 8];
            const bf16x8 b1 = *(const bf16x8*)&Bsh[16 + ln15][ks + quad * 8];
            const bf16x8 b2 = *(const bf16x8*)&Bsh[32 + ln15][ks + quad * 8];
            const bf16x8 b3 = *(const bf16x8*)&Bsh[48 + ln15][ks + quad * 8];
            a0 = __builtin_amdgcn_mfma_f32_16x16x32_bf16(af, b0, a0, 0, 0, 0);
            a1 = __builtin_amdgcn_mfma_f32_16x16x32_bf16(af, b1, a1, 0, 0, 0);
            a2 = __builtin_amdgcn_mfma_f32_16x16x32_bf16(af, b2, a2, 0, 0, 0);
            a3 = __builtin_amdgcn_mfma_f32_16x16x32_bf16(af, b3, a3, 0, 0, 0);
        }
        __syncthreads();
    }

    const int jv = j0 + ln15;
    const float bi  = bsum1[jv],          bfv = bsum1[NH + jv];
    const float bg  = bsum1[2 * NH + jv], bo  = bsum1[3 * NH + jv];
    float hv[4];
    #pragma unroll
    for (int r = 0; r < 4; ++r) {
        const int m = m0 + wv * 16 + quad * 4 + r;
        const float gi = a0[r] + bi;
        const float gf = a1[r] + bfv;
        const float gg = a2[r] + bg;
        const float go = a3[r] + bo;
        float cv = c2[(size_t)m * NH + jv];
        cv = lstm9_sig(gf) * cv + lstm9_sig(gi) * tanhf(gg);
        c2[(size_t)m * NH + jv] = cv;
        hv[r] = lstm9_sig(go) * tanhf(cv);
        h2next[(size_t)m * NH + jv] = lstm9_f2b(hv[r]);
    }

    if (ycol >= 0) {
        const float wl = wlinf[jv];
        #pragma unroll
        for (int r = 0; r < 4; ++r)
            redsh[wv * 16 + quad * 4 + r][ln15] = hv[r] * wl;
        __syncthreads();
        if (tid < 64) {
            float s = 0.0f;
            #pragma unroll
            for (int j = 0; j < 16; ++j) s += redsh[tid][j];
            atomicAdd(&ybuf[(size_t)(m0 + tid) * NT + ycol], s);
        }
    }
}

// ---- y0 head (reference quirk): y[:,0] = b_lin + c2 @ w_lin (CELL state!) ----
__global__ __launch_bounds__(256) void lstm9_head(
    const float* __restrict__ c2, const float* __restrict__ wlin,
    const float* __restrict__ blin, float* __restrict__ ybuf)
{
    __shared__ float acc[256];
    const int b   = blockIdx.x;
    const int tid = threadIdx.x;
    acc[tid] = c2[(size_t)b * NH + tid]       * wlin[tid]
             + c2[(size_t)b * NH + tid + 256] * wlin[tid + 256];
    __syncthreads();
    for (int off = 128; off > 0; off >>= 1) {
        if (tid < off) acc[tid] += acc[tid + off];
        __syncthreads();
    }
    if (tid == 0) ybuf[(size_t)b * NT] = blin[0] + acc[0];
}

// ---- final: all predictions to d_out as fp32 ----
__global__ void lstm9_emit(const float* __restrict__ ybuf, float* __restrict__ out) {
    const int i = blockIdx.x * blockDim.x + threadIdx.x;
    if (i < NB * NT) out[i] = ybuf[i];
}

extern "C" void kernel_launch(void* const* d_in, const int* in_sizes, int n_in,
                              void* d_out, int out_size, void* d_ws, size_t ws_size,
                              hipStream_t stream)
{
    int base = 3;
    if (!(n_in > 3 && in_sizes[3] == 4 * NH)) {
        for (int i = 1; i + 9 < n_in; ++i)
            if (in_sizes[i] == 4 * NH) { base = i; break; }
    }
    const float* xin  = (const float*)d_in[0];
    const float* wih0 = (const float*)d_in[base + 0];
    const float* whh0 = (const float*)d_in[base + 1];
    const float* bih0 = (const float*)d_in[base + 2];
    const float* bhh0 = (const float*)d_in[base + 3];
    const float* wih1 = (const float*)d_in[base + 4];
    const float* whh1 = (const float*)d_in[base + 5];
    const float* bih1 = (const float*)d_in[base + 6];
    const float* bhh1 = (const float*)d_in[base + 7];
    const float* wlin = (const float*)d_in[base + 8];
    const float* blin = (const float*)d_in[base + 9];
    float* outf = (float*)d_out;

    // ws layout (~10.3 MB): bf16 weights | bf16 h ping-pong | fp32 c, bias, y.
    const size_t NW = (size_t)4 * NH * NH;
    const size_t S  = (size_t)NB * NH;
    unsigned short* wb0  = (unsigned short*)d_ws;
    unsigned short* wb1i = wb0 + NW;
    unsigned short* wb1h = wb1i + NW;
    unsigned short* h1b0 = wb1h + NW;
    unsigned short* h1b1 = h1b0 + S;
    unsigned short* h2b0 = h1b1 + S;
    unsigned short* h2b1 = h2b0 + S;
    float* bsum0 = (float*)(h2b1 + S);
    float* bsum1 = bsum0 + 4 * NH;
    float* c1    = bsum1 + 4 * NH;
    float* c2    = c1 + S;
    float* ybuf  = c2 + S;
    unsigned short* h1p[2] = { h1b0, h1b1 };
    unsigned short* h2p[2] = { h2b0, h2b1 };

    lstm9_mark<<<(NB * NT + 255) / 256, 256, 0, stream>>>(outf);
    lstm9_prep<<<1024, 256, 0, stream>>>(whh0, wih1, whh1, bih0, bhh0, bih1, bhh1,
                                         blin, wb0, wb1i, wb1h, bsum0, bsum1,
                                         h1b0, c1, ybuf);

    dim3 grid(NH / 16, NB / 64);   // (32 j, 8 m): blk%8 spreads j over XCDs
    int p = 0;
    // Phase 1: teacher-forced; heads disabled (y0 handled by lstm9_head).
    for (int t = 0; t < NT; ++t) {
        lstm9_layer0<<<grid, 256, 0, stream>>>(xin, ybuf, t, 0, -1, outf,
                                               h1p[p], h1p[p ^ 1], c1,
                                               wb0, bsum0, wih0);
        lstm9_layer1<<<grid, 256, 0, stream>>>(h1p[p ^ 1], h2p[p], h2p[p ^ 1], c2,
                                               wb1i, wb1h, bsum1, wlin, ybuf, -1);
        p ^= 1;
    }
    // Reference quirk: first prediction from the CELL state c2.
    lstm9_head<<<NB, 256, 0, stream>>>(c2, wlin, blin, ybuf);
    // Phase 2: autoregressive; layer0 consumes y[:,k-1] and publishes it.
    for (int k = 1; k < NT; ++k) {
        lstm9_layer0<<<grid, 256, 0, stream>>>(xin, ybuf, k - 1, 1, k - 1, outf,
                                               h1p[p], h1p[p ^ 1], c1,
                                               wb0, bsum0, wih0);
        lstm9_layer1<<<grid, 256, 0, stream>>>(h1p[p ^ 1], h2p[p], h2p[p ^ 1], c2,
                                               wb1i, wb1h, bsum1, wlin, ybuf, k);
        p ^= 1;
    }
    lstm9_emit<<<(NB * NT + 255) / 256, 256, 0, stream>>>(ybuf, outf);
}